// Round 15
// baseline (4370.547 us; speedup 1.0000x reference)
//
#include <hip/hip_runtime.h>
#include <cstdint>
#include <cstddef>

#define BN_EPS 1e-5f
#define L2E   1.4426950408889634f
#define L2E2  2.8853900817779268f

typedef __attribute__((ext_vector_type(8))) short  bf16x8;
typedef __attribute__((ext_vector_type(4))) float  f32x4;
typedef __attribute__((ext_vector_type(4))) unsigned u32x4;
typedef __attribute__((ext_vector_type(2))) unsigned u32x2;
typedef __attribute__((ext_vector_type(8))) _Float16 f16x8;
typedef __attribute__((ext_vector_type(4))) _Float16 f16x4;

__device__ __forceinline__ float sigf(float x) {
    return 1.0f / (1.0f + __expf(-x));
}
__device__ __forceinline__ float tanhfast(float x) {
    return 2.0f / (1.0f + __expf(-2.0f * x)) - 1.0f;
}
__device__ __forceinline__ unsigned bfr(float x) {  // f32 -> bf16 bits (RNE)
    unsigned u = __float_as_uint(x);
    return (u + 0x7fffu + ((u >> 16) & 1u)) >> 16;
}
__device__ __forceinline__ bf16x8 pack8(float4 a, float4 b) {  // ascending k
    u32x4 u;
    u.x = (bfr(a.y) << 16) | bfr(a.x);
    u.y = (bfr(a.w) << 16) | bfr(a.z);
    u.z = (bfr(b.y) << 16) | bfr(b.x);
    u.w = (bfr(b.w) << 16) | bfr(b.z);
    return __builtin_bit_cast(bf16x8, u);
}
__device__ __forceinline__ float rcp_f(float x) {
    return __builtin_amdgcn_rcpf(x);
}
__device__ __forceinline__ float exp2_f(float x) {
    return __builtin_amdgcn_exp2f(x);
}
__device__ __forceinline__ unsigned cvtpk_bf16(float lo, float hi) {
    unsigned r; asm("v_cvt_pk_bf16_f32 %0, %1, %2" : "=v"(r) : "v"(lo), "v"(hi));
    return r;
}

// LDS-only barrier: global loads/stores stay in flight across steps.
#define LBAR()                                                   \
    do {                                                         \
        asm volatile("s_waitcnt lgkmcnt(0)" ::: "memory");       \
        __builtin_amdgcn_s_barrier();                            \
        asm volatile("" ::: "memory");                           \
    } while (0)

// ---------------- conv1 (fallback, channel-major y1[B,32,T]) ----------------
__global__ __launch_bounds__(256) void k_conv1(
    const float* __restrict__ x, const float* __restrict__ w,
    const float* __restrict__ g, const float* __restrict__ bb,
    const float* __restrict__ m, const float* __restrict__ v,
    float* __restrict__ y1, int B, int T)
{
    const int TT = 256;
    __shared__ float xs[(TT + 6) * 9];
    const int b = blockIdx.y;
    const int t0 = blockIdx.x * TT;
    const int tid = threadIdx.x;

    for (int idx = tid; idx < (TT + 6) * 9; idx += 256) {
        int row = idx / 9, col = idx - row * 9;
        int tg = t0 - 3 + row;
        xs[idx] = (tg >= 0 && tg < T) ? x[((size_t)b * T + tg) * 9 + col] : 0.0f;
    }
    __syncthreads();

    float xv[63];
#pragma unroll
    for (int k = 0; k < 7; ++k)
#pragma unroll
        for (int ci = 0; ci < 9; ++ci)
            xv[k * 9 + ci] = xs[(tid + k) * 9 + ci];

    const int t = t0 + tid;
    for (int co = 0; co < 32; ++co) {
        float acc = 0.0f;
#pragma unroll
        for (int ci = 0; ci < 9; ++ci)
#pragma unroll
            for (int k = 0; k < 7; ++k)
                acc += xv[k * 9 + ci] * w[(co * 9 + ci) * 7 + k];
        float sc = g[co] / sqrtf(v[co] + BN_EPS);
        float bf = bb[co] - m[co] * sc;
        float o = acc * sc + bf;
        y1[((size_t)b * 32 + co) * T + t] = o > 0.0f ? o : 0.0f;
    }
}

// ---------------- conv1 (fast path, t-major y1t[B,T,32]) --------------------
__global__ __launch_bounds__(256) void k_conv1t(
    const float* __restrict__ x, const float* __restrict__ w,
    const float* __restrict__ g, const float* __restrict__ bb,
    const float* __restrict__ m, const float* __restrict__ v,
    float* __restrict__ y1t, int B, int T)
{
    const int TT = 256;
    __shared__ float xs[(TT + 6) * 9];
    const int b = blockIdx.y;
    const int t0 = blockIdx.x * TT;
    const int tid = threadIdx.x;

    for (int idx = tid; idx < (TT + 6) * 9; idx += 256) {
        int row = idx / 9, col = idx - row * 9;
        int tg = t0 - 3 + row;
        xs[idx] = (tg >= 0 && tg < T) ? x[((size_t)b * T + tg) * 9 + col] : 0.0f;
    }
    __syncthreads();

    float xv[63];
#pragma unroll
    for (int k = 0; k < 7; ++k)
#pragma unroll
        for (int ci = 0; ci < 9; ++ci)
            xv[k * 9 + ci] = xs[(tid + k) * 9 + ci];

    const int t = t0 + tid;
    float* orow = y1t + ((size_t)b * T + t) * 32;
    for (int co = 0; co < 32; ++co) {
        float acc = 0.0f;
#pragma unroll
        for (int ci = 0; ci < 9; ++ci)
#pragma unroll
            for (int k = 0; k < 7; ++k)
                acc += xv[k * 9 + ci] * w[(co * 9 + ci) * 7 + k];
        float sc = g[co] / sqrtf(v[co] + BN_EPS);
        float bf = bb[co] - m[co] * sc;
        float o = acc * sc + bf;
        orow[co] = o > 0.0f ? o : 0.0f;
    }
}

// -------- conv2 (fallback, scalar): y1[B,32,T] -> y2t[B,T,64] ---------------
__global__ __launch_bounds__(256) void k_conv2(
    const float* __restrict__ y1, const float* __restrict__ w,
    const float* __restrict__ g, const float* __restrict__ bb,
    const float* __restrict__ m, const float* __restrict__ v,
    float* __restrict__ y2t, int B, int T)
{
    const int TT = 256;
    __shared__ float ys[32 * (TT + 6)];
    const int b = blockIdx.y;
    const int t0 = blockIdx.x * TT;
    const int tid = threadIdx.x;

    for (int idx = tid; idx < 32 * (TT + 6); idx += 256) {
        int ci = idx / (TT + 6), i = idx - ci * (TT + 6);
        int tg = t0 - 3 + i;
        ys[idx] = (tg >= 0 && tg < T) ? y1[((size_t)b * 32 + ci) * T + tg] : 0.0f;
    }
    __syncthreads();

    float acc[64];
#pragma unroll
    for (int co = 0; co < 64; ++co) acc[co] = 0.0f;

    for (int ci = 0; ci < 32; ++ci) {
        float yw[7];
#pragma unroll
        for (int k = 0; k < 7; ++k) yw[k] = ys[ci * (TT + 6) + tid + k];
#pragma unroll
        for (int co = 0; co < 64; ++co)
#pragma unroll
            for (int k = 0; k < 7; ++k)
                acc[co] += yw[k] * w[(co * 32 + ci) * 7 + k];
    }

    const int t = t0 + tid;
    float* orow = y2t + ((size_t)b * T + t) * 64;
    for (int co = 0; co < 64; co += 4) {
        float4 o;
        float s0 = g[co+0] / sqrtf(v[co+0] + BN_EPS);
        float s1 = g[co+1] / sqrtf(v[co+1] + BN_EPS);
        float s2 = g[co+2] / sqrtf(v[co+2] + BN_EPS);
        float s3 = g[co+3] / sqrtf(v[co+3] + BN_EPS);
        o.x = acc[co+0] * s0 + (bb[co+0] - m[co+0] * s0);
        o.y = acc[co+1] * s1 + (bb[co+1] - m[co+1] * s1);
        o.z = acc[co+2] * s2 + (bb[co+2] - m[co+2] * s2);
        o.w = acc[co+3] * s3 + (bb[co+3] - m[co+3] * s3);
        o.x = o.x > 0.f ? o.x : 0.f;
        o.y = o.y > 0.f ? o.y : 0.f;
        o.z = o.z > 0.f ? o.z : 0.f;
        o.w = o.w > 0.f ? o.w : 0.f;
        *reinterpret_cast<float4*>(orow + co) = o;
    }
}

// ---- pack conv2 weights -> bf16 frag order, BN scale folded (1792 tuples) --
// A[co][k'=kk*32+ci]; frag (rt<4, kk<7, lane): lane(c,q) holds
// A[rt*16+c][kk*32 + q*8 + j].
__global__ __launch_bounds__(256) void k_pack_w2(
    const float* __restrict__ w2, const float* __restrict__ g,
    const float* __restrict__ v, unsigned* __restrict__ apk2)
{
    int tu = blockIdx.x * 256 + threadIdx.x;
    if (tu >= 4 * 7 * 64) return;
    int lane = tu & 63, kk = (tu >> 6) % 7, rt = tu / (7 * 64);
    int c = lane & 15, q = lane >> 4;
    int co = rt * 16 + c, ci0 = q * 8;
    float sc = g[co] / sqrtf(v[co] + BN_EPS);
    float4 a, b;
    a.x = w2[(co * 32 + ci0 + 0) * 7 + kk] * sc;
    a.y = w2[(co * 32 + ci0 + 1) * 7 + kk] * sc;
    a.z = w2[(co * 32 + ci0 + 2) * 7 + kk] * sc;
    a.w = w2[(co * 32 + ci0 + 3) * 7 + kk] * sc;
    b.x = w2[(co * 32 + ci0 + 4) * 7 + kk] * sc;
    b.y = w2[(co * 32 + ci0 + 5) * 7 + kk] * sc;
    b.z = w2[(co * 32 + ci0 + 6) * 7 + kk] * sc;
    b.w = w2[(co * 32 + ci0 + 7) * 7 + kk] * sc;
    bf16x8 p = pack8(a, b);
    *reinterpret_cast<u32x4*>(apk2 + (size_t)tu * 4) = __builtin_bit_cast(u32x4, p);
}

// --------- conv2 via MFMA : y1t[B,T,32] -> y2t[B,T,64] ----------------------
// GEMM M=64 (4 row-tiles = 4 waves), N=64 t/block, K=224 (7 ksteps).
__global__ __launch_bounds__(256) void k_conv2m(
    const float* __restrict__ y1t, const unsigned* __restrict__ apk2,
    const float* __restrict__ g, const float* __restrict__ bb,
    const float* __restrict__ m, const float* __restrict__ v,
    float* __restrict__ y2t, int B, int T)
{
    __shared__ __align__(16) unsigned short yst[70 * 40];  // bf16, 5.6 KB
    const int b  = blockIdx.y;
    const int t0 = blockIdx.x * 64;
    const int tid = threadIdx.x;
    const int wv = tid >> 6;            // row-tile
    const int lane = tid & 63;
    const int c = lane & 15, q = lane >> 4;

    for (int i = tid; i < 70 * 4; i += 256) {
        int row = i >> 2, cg = (i & 3) * 8;
        int tg = t0 - 3 + row;
        bf16x8 p;
        if (tg >= 0 && tg < T) {
            const float* src = y1t + ((size_t)b * T + tg) * 32 + cg;
            float4 a0 = *reinterpret_cast<const float4*>(src);
            float4 a1 = *reinterpret_cast<const float4*>(src + 4);
            p = pack8(a0, a1);
        } else {
            u32x4 z = {0u, 0u, 0u, 0u};
            p = __builtin_bit_cast(bf16x8, z);
        }
        *reinterpret_cast<u32x4*>(&yst[row * 40 + cg]) = __builtin_bit_cast(u32x4, p);
    }
    __syncthreads();

    f32x4 acc[4] = {{0,0,0,0},{0,0,0,0},{0,0,0,0},{0,0,0,0}};
#pragma unroll
    for (int kk = 0; kk < 7; ++kk) {
        u32x4 au = *reinterpret_cast<const u32x4*>(
            apk2 + ((size_t)(wv * 7 + kk) * 64 + lane) * 4);
        bf16x8 av = __builtin_bit_cast(bf16x8, au);
#pragma unroll
        for (int nt = 0; nt < 4; ++nt) {
            u32x4 bu = *reinterpret_cast<const u32x4*>(
                &yst[(nt * 16 + c + kk) * 40 + q * 8]);
            bf16x8 bv = __builtin_bit_cast(bf16x8, bu);
            acc[nt] = __builtin_amdgcn_mfma_f32_16x16x32_bf16(av, bv, acc[nt], 0, 0, 0);
        }
    }

    const int co0 = wv * 16 + q * 4;
    float bf4[4];
#pragma unroll
    for (int r = 0; r < 4; ++r) {
        float sc = g[co0 + r] / sqrtf(v[co0 + r] + BN_EPS);
        bf4[r] = bb[co0 + r] - m[co0 + r] * sc;
    }
#pragma unroll
    for (int nt = 0; nt < 4; ++nt) {
        const int t = t0 + nt * 16 + c;
        float4 o;
        o.x = acc[nt][0] + bf4[0]; o.x = o.x > 0.f ? o.x : 0.f;
        o.y = acc[nt][1] + bf4[1]; o.y = o.y > 0.f ? o.y : 0.f;
        o.z = acc[nt][2] + bf4[2]; o.z = o.z > 0.f ? o.z : 0.f;
        o.w = acc[nt][3] + bf4[3]; o.w = o.w > 0.f ? o.w : 0.f;
        *reinterpret_cast<float4*>(y2t + ((size_t)b * T + t) * 64 + co0) = o;
    }
}

// ---- pack conv3 weights -> bf16 frag order, BN scale folded (7168 tuples) --
__global__ __launch_bounds__(256) void k_pack_w3(
    const float* __restrict__ w3, const float* __restrict__ g,
    const float* __restrict__ v, unsigned* __restrict__ apk)
{
    int tu = blockIdx.x * 256 + threadIdx.x;
    if (tu >= 8 * 14 * 64) return;
    int lane = tu & 63, ks = (tu >> 6) % 14, rt = tu / (14 * 64);
    int c = lane & 15, q = lane >> 4;
    int co = rt * 16 + c, kk = ks >> 1, ci0 = (ks & 1) * 32 + q * 8;
    float sc = g[co] / sqrtf(v[co] + BN_EPS);
    float4 a, b;
    a.x = w3[(co * 64 + ci0 + 0) * 7 + kk] * sc;
    a.y = w3[(co * 64 + ci0 + 1) * 7 + kk] * sc;
    a.z = w3[(co * 64 + ci0 + 2) * 7 + kk] * sc;
    a.w = w3[(co * 64 + ci0 + 3) * 7 + kk] * sc;
    b.x = w3[(co * 64 + ci0 + 4) * 7 + kk] * sc;
    b.y = w3[(co * 64 + ci0 + 5) * 7 + kk] * sc;
    b.z = w3[(co * 64 + ci0 + 6) * 7 + kk] * sc;
    b.w = w3[(co * 64 + ci0 + 7) * 7 + kk] * sc;
    bf16x8 p = pack8(a, b);
    *reinterpret_cast<u32x4*>(apk + (size_t)tu * 4) = __builtin_bit_cast(u32x4, p);
}

// ---- pack W_ih -> bf16 frag order, gate exp2-scales folded (8192 tuples) ---
__global__ __launch_bounds__(256) void k_pack_wih(
    const float* __restrict__ w_ih, unsigned* __restrict__ wpk)
{
    int tu = blockIdx.x * 256 + threadIdx.x;
    if (tu >= 4 * 8 * 4 * 64) return;
    int lane = tu & 63, ks = (tu >> 6) & 3, rt = (tu >> 8) & 7, gg = tu >> 11;
    int c = lane & 15, q = lane >> 4;
    int row = gg * 128 + rt * 16 + c;
    float sc = (gg == 2) ? L2E2 : -L2E;
    const float* src = w_ih + (size_t)row * 128 + ks * 32 + q * 8;
    float4 a = *reinterpret_cast<const float4*>(src);
    float4 b = *reinterpret_cast<const float4*>(src + 4);
    a.x *= sc; a.y *= sc; a.z *= sc; a.w *= sc;
    b.x *= sc; b.y *= sc; b.z *= sc; b.w *= sc;
    bf16x8 p = pack8(a, b);
    *reinterpret_cast<u32x4*>(wpk + (size_t)tu * 4) = __builtin_bit_cast(u32x4, p);
}

// ------------- conv3 via MFMA : y2t[B,T,64] -> feat[B,T,128] ----------------
__global__ __launch_bounds__(512) void k_conv3m(
    const float* __restrict__ y2t, const unsigned* __restrict__ apk,
    const float* __restrict__ g, const float* __restrict__ bb,
    const float* __restrict__ m, const float* __restrict__ v,
    float* __restrict__ feat, int B, int T)
{
    __shared__ __align__(16) unsigned short yst[70 * 72];  // bf16, 9.8 KB
    const int b  = blockIdx.y;
    const int t0 = blockIdx.x * 64;
    const int tid = threadIdx.x;
    const int wv = tid >> 6;            // row-tile
    const int lane = tid & 63;
    const int c = lane & 15, q = lane >> 4;

    for (int i = tid; i < 70 * 8; i += 512) {
        int row = i >> 3, cg = (i & 7) * 8;
        int tg = t0 - 3 + row;
        bf16x8 p;
        if (tg >= 0 && tg < T) {
            const float* src = y2t + ((size_t)b * T + tg) * 64 + cg;
            float4 a0 = *reinterpret_cast<const float4*>(src);
            float4 a1 = *reinterpret_cast<const float4*>(src + 4);
            p = pack8(a0, a1);
        } else {
            u32x4 z = {0u, 0u, 0u, 0u};
            p = __builtin_bit_cast(bf16x8, z);
        }
        *reinterpret_cast<u32x4*>(&yst[row * 72 + cg]) = __builtin_bit_cast(u32x4, p);
    }
    __syncthreads();

    f32x4 acc[4] = {{0,0,0,0},{0,0,0,0},{0,0,0,0},{0,0,0,0}};
#pragma unroll
    for (int ks = 0; ks < 14; ++ks) {
        const int kk = ks >> 1, ci0 = (ks & 1) * 32 + q * 8;
        u32x4 au = *reinterpret_cast<const u32x4*>(
            apk + ((size_t)(wv * 14 + ks) * 64 + lane) * 4);
        bf16x8 av = __builtin_bit_cast(bf16x8, au);
#pragma unroll
        for (int nt = 0; nt < 4; ++nt) {
            u32x4 bu = *reinterpret_cast<const u32x4*>(
                &yst[(nt * 16 + c + kk) * 72 + ci0]);
            bf16x8 bv = __builtin_bit_cast(bf16x8, bu);
            acc[nt] = __builtin_amdgcn_mfma_f32_16x16x32_bf16(av, bv, acc[nt], 0, 0, 0);
        }
    }

    const int co0 = wv * 16 + q * 4;
    float bf4[4];
#pragma unroll
    for (int r = 0; r < 4; ++r) {
        float sc = g[co0 + r] / sqrtf(v[co0 + r] + BN_EPS);
        bf4[r] = bb[co0 + r] - m[co0 + r] * sc;
    }
#pragma unroll
    for (int nt = 0; nt < 4; ++nt) {
        const int t = t0 + nt * 16 + c;
        float4 o;
        o.x = acc[nt][0] + bf4[0]; o.x = o.x > 0.f ? o.x : 0.f;
        o.y = acc[nt][1] + bf4[1]; o.y = o.y > 0.f ? o.y : 0.f;
        o.z = acc[nt][2] + bf4[2]; o.z = o.z > 0.f ? o.z : 0.f;
        o.w = acc[nt][3] + bf4[3]; o.w = o.w > 0.f ? o.w : 0.f;
        *reinterpret_cast<float4*>(feat + ((size_t)b * T + t) * 128 + co0) = o;
    }
}

// ----------- x-projection GEMM: xp = scale_g*(W_ih·x + b) (f16) -------------
__global__ __launch_bounds__(256) void k_xpre(
    const float* __restrict__ feat, const unsigned* __restrict__ wpk,
    const float* __restrict__ b_ih, const float* __restrict__ b_hh,
    _Float16* __restrict__ xp, int T)
{
    const int b   = blockIdx.y;
    const int t0  = blockIdx.x * 32;
    const int tid = threadIdx.x;
    const int wv2 = tid >> 6;      // gate g
    const int lane = tid & 63;
    const int c2 = lane & 15;
    const int q2 = lane >> 4;
    const float sc = (wv2 == 2) ? L2E2 : -L2E;

    bf16x8 btile[2][4];
#pragma unroll
    for (int tc = 0; tc < 2; ++tc) {
        const float* xrow = feat + ((size_t)b * T + t0 + tc * 16 + c2) * 128;
#pragma unroll
        for (int ks = 0; ks < 4; ++ks) {
            float4 x0 = *reinterpret_cast<const float4*>(xrow + ks * 32 + q2 * 8);
            float4 x1 = *reinterpret_cast<const float4*>(xrow + ks * 32 + q2 * 8 + 4);
            btile[tc][ks] = pack8(x0, x1);
        }
    }

#pragma unroll
    for (int rt = 0; rt < 8; ++rt) {
        bf16x8 a[4];
#pragma unroll
        for (int ks = 0; ks < 4; ++ks) {
            u32x4 au = *reinterpret_cast<const u32x4*>(
                wpk + ((size_t)(((wv2 * 8 + rt) * 4 + ks) * 64) + lane) * 4);
            a[ks] = __builtin_bit_cast(bf16x8, au);
        }
        const int gr0 = wv2 * 128 + rt * 16 + q2 * 4;
        float4 bi = *reinterpret_cast<const float4*>(b_ih + gr0);
        float4 bh = *reinterpret_cast<const float4*>(b_hh + gr0);
        f32x4 bias = {(bi.x + bh.x) * sc, (bi.y + bh.y) * sc,
                      (bi.z + bh.z) * sc, (bi.w + bh.w) * sc};

#pragma unroll
        for (int tc = 0; tc < 2; ++tc) {
            f32x4 acc = bias;
#pragma unroll
            for (int ks = 0; ks < 4; ++ks)
                acc = __builtin_amdgcn_mfma_f32_16x16x32_bf16(a[ks], btile[tc][ks], acc, 0, 0, 0);
            const int t = t0 + tc * 16 + c2;
            f16x4 hv = {(_Float16)acc[0], (_Float16)acc[1],
                        (_Float16)acc[2], (_Float16)acc[3]};
            *reinterpret_cast<f16x4*>(
                xp + ((size_t)b * T + t) * 512 + (rt * 4 + q2) * 16 + wv2 * 4) = hv;
        }
    }
}

// --------------------- reversed-time LSTM (MFMA, K=128) ---------------------
// R15: pointer-walking addresses (no per-step 64-bit mads; OOB prefetches
// land in ws and are never consumed) + trans-fused pointwise:
// sig(a)*tanh(b) = (e_b - 1) * rcp((1+e_a)(1+e_b))  -> 8 trans/unit (was 10).
// fminf clamps guard numerator exp2 overflow (inf*0 = NaN).
#define SWZ(b) (((b) & 7) << 4)

#define LSTM_BODY(RBUF, WBUF, Q0, Q1, PF_OFF, OUT_OFF)                        \
    {                                                                          \
        f32x4 acc0 = {(float)Q0[0], (float)Q0[1], (float)Q0[2], (float)Q0[3]}; \
        f32x4 acc1 = {(float)Q0[4], (float)Q0[5], (float)Q0[6], (float)Q0[7]}; \
        f32x4 acc2 = {(float)Q1[0], (float)Q1[1], (float)Q1[2], (float)Q1[3]}; \
        f32x4 acc3 = {(float)Q1[4], (float)Q1[5], (float)Q1[6], (float)Q1[7]}; \
        Q0 = *reinterpret_cast<const f16x8*>(xq + (PF_OFF));                   \
        Q1 = *reinterpret_cast<const f16x8*>(xq + (PF_OFF) + 8);               \
        const char* hrow_ = (const char*)&RBUF[c][0];                          \
        _Pragma("unroll")                                                      \
        for (int ks = 0; ks < 4; ++ks) {                                       \
            u32x4 bq = *reinterpret_cast<const u32x4*>(                        \
                hrow_ + ((ks * 64 + q * 16) ^ SWZ(c)));                        \
            bf16x8 bf = __builtin_bit_cast(bf16x8, bq);                        \
            acc0 = __builtin_amdgcn_mfma_f32_16x16x32_bf16(afr[0][ks], bf, acc0, 0, 0, 0); \
            acc1 = __builtin_amdgcn_mfma_f32_16x16x32_bf16(afr[1][ks], bf, acc1, 0, 0, 0); \
            acc2 = __builtin_amdgcn_mfma_f32_16x16x32_bf16(afr[2][ks], bf, acc2, 0, 0, 0); \
            acc3 = __builtin_amdgcn_mfma_f32_16x16x32_bf16(afr[3][ks], bf, acc3, 0, 0, 0); \
        }                                                                      \
        float h4_[4];                                                          \
        _Pragma("unroll")                                                      \
        for (int r = 0; r < 4; ++r) {                                          \
            float eI = exp2_f(acc0[r]);                                        \
            float eF = exp2_f(acc1[r]);                                        \
            float eG = exp2_f(fminf(acc2[r], 120.0f));                         \
            float gf = rcp_f(1.0f + eF);                                       \
            float ig = (eG - 1.0f) * rcp_f((1.0f + eI) * (1.0f + eG));         \
            cst[r] = fmaf(gf, cst[r], ig);                                     \
            float eC = exp2_f(fminf(cst[r] * L2E2, 120.0f));                   \
            float eO = exp2_f(acc3[r]);                                        \
            h4_[r] = (eC - 1.0f) * rcp_f((1.0f + eO) * (1.0f + eC));           \
        }                                                                      \
        if (valid) {                                                           \
            *reinterpret_cast<float4*>(po + (OUT_OFF)) =                       \
                make_float4(h4_[0], h4_[1], h4_[2], h4_[3]);                   \
            u32x2 hw_;                                                         \
            hw_.x = cvtpk_bf16(h4_[0], h4_[1]);                                \
            hw_.y = cvtpk_bf16(h4_[2], h4_[3]);                                \
            *reinterpret_cast<u32x2*>(                                         \
                (char*)&WBUF[c][0] + ((u0 * 2) ^ SWZ(c))) = hw_;               \
        }                                                                      \
    }

__global__ __launch_bounds__(512) void k_lstm8(
    const _Float16* __restrict__ xp, const float* __restrict__ w_hh,
    float* __restrict__ out, int T)
{
    __shared__ __align__(16) unsigned short h_lds[2][16][128];  // bf16, 8 KB

    const int tid  = threadIdx.x;
    const int bk   = blockIdx.x;          // batches [bk*8, bk*8+8)
    const int wv   = tid >> 6;
    const int lane = tid & 63;
    const int c    = lane & 15;
    const int q    = lane >> 4;
    const int u0   = wv * 16 + q * 4;
    const bool valid = (c < 8);
    const int b    = bk * 8 + (c & 7);

    bf16x8 afr[4][4];
#pragma unroll
    for (int g = 0; g < 4; ++g) {
        const float sc = (g == 2) ? L2E2 : -L2E;
        const float* wr = w_hh + (size_t)(g * 128 + wv * 16 + c) * 128;
#pragma unroll
        for (int ks = 0; ks < 4; ++ks) {
            float4 w0 = *reinterpret_cast<const float4*>(wr + ks * 32 + q * 8);
            float4 w1 = *reinterpret_cast<const float4*>(wr + ks * 32 + q * 8 + 4);
            w0.x *= sc; w0.y *= sc; w0.z *= sc; w0.w *= sc;
            w1.x *= sc; w1.y *= sc; w1.z *= sc; w1.w *= sc;
            afr[g][ks] = pack8(w0, w1);
        }
    }

    {
        u32x2 z = {0u, 0u};
        *reinterpret_cast<u32x2*>((char*)&h_lds[0][c][0] + ((u0 * 2) ^ SWZ(c))) = z;
        *reinterpret_cast<u32x2*>((char*)&h_lds[1][c][0] + ((u0 * 2) ^ SWZ(c))) = z;
    }
    f32x4 cst = {0.f, 0.f, 0.f, 0.f};

    // walking pointers: xq = xp row for body-A's step; po = out row ditto.
    const _Float16* xq = xp + ((size_t)b * T + (T - 1)) * 512 + (wv * 4 + q) * 16;
    float* po = out + ((size_t)b * T + (T - 1)) * 128 + u0;

    f16x8 PA0 = *reinterpret_cast<const f16x8*>(xq);
    f16x8 PA1 = *reinterpret_cast<const f16x8*>(xq + 8);
    f16x8 PB0 = *reinterpret_cast<const f16x8*>(xq - 512);
    f16x8 PB1 = *reinterpret_cast<const f16x8*>(xq - 512 + 8);
    __syncthreads();

    for (int it = 0; it < T / 2; ++it) {
        LSTM_BODY(h_lds[0], h_lds[1], PA0, PA1, -1024, 0);     // step t
        LBAR();
        LSTM_BODY(h_lds[1], h_lds[0], PB0, PB1, -1536, -128);  // step t-1
        LBAR();
        xq -= 1024;
        po -= 256;
    }
}

// ------------------- fallback LSTM (K=256 interleaved) ----------------------
__global__ __launch_bounds__(512) void k_lstm4(
    const float* __restrict__ feat, const float* __restrict__ w_ih,
    const float* __restrict__ w_hh, const float* __restrict__ b_ih,
    const float* __restrict__ b_hh, float* __restrict__ out, int T)
{
    __shared__ __align__(16) unsigned hx[2][16][128];
    __shared__ __align__(16) u32x4 wlds[8 * 2 * 8 * 64];

    const int tid  = threadIdx.x;
    const int bk   = blockIdx.x;
    const int wv   = tid >> 6;
    const int lane = tid & 63;
    const int c    = lane & 15;
    const int q    = lane >> 4;

    bf16x8 afr[2][8];
#pragma unroll
    for (int g = 0; g < 4; ++g) {
        const int row = g * 128 + wv * 16 + c;
#pragma unroll
        for (int ks = 0; ks < 8; ++ks) {
            const int m0 = ks * 16 + q * 4;
            float4 h4 = *reinterpret_cast<const float4*>(w_hh + (size_t)row * 128 + m0);
            float4 i4 = *reinterpret_cast<const float4*>(w_ih + (size_t)row * 128 + m0);
            u32x4 u;
            u.x = (bfr(i4.x) << 16) | bfr(h4.x);
            u.y = (bfr(i4.y) << 16) | bfr(h4.y);
            u.z = (bfr(i4.z) << 16) | bfr(h4.z);
            u.w = (bfr(i4.w) << 16) | bfr(h4.w);
            if (g < 2)
                afr[g][ks] = __builtin_bit_cast(bf16x8, u);
            else
                wlds[((wv * 2 + (g - 2)) * 8 + ks) * 64 + lane] = u;
        }
    }

    float bias[4][4];
#pragma unroll
    for (int g = 0; g < 4; ++g)
#pragma unroll
        for (int r = 0; r < 4; ++r) {
            const int j = wv * 16 + q * 4 + r;
            bias[g][r] = b_ih[g * 128 + j] + b_hh[g * 128 + j];
        }

    const size_t fbase = ((size_t)(bk * 16 + c)) * T;
    const int u0 = wv * 16 + q * 4;

    {
        float4 x0 = *reinterpret_cast<const float4*>(feat + (fbase + (T - 1)) * 128 + u0);
        u32x4 u;
        u.x = bfr(x0.x) << 16;
        u.y = bfr(x0.y) << 16;
        u.z = bfr(x0.z) << 16;
        u.w = bfr(x0.w) << 16;
        *reinterpret_cast<u32x4*>((char*)&hx[0][c][0] + ((u0 * 4) ^ SWZ(c))) = u;
    }
    f32x4 cst = {0.f, 0.f, 0.f, 0.f};
    __syncthreads();

    int cur = 0;
    for (int t = T - 1; t >= 0; --t) {
        const int tp = (t > 0) ? t - 1 : 0;
        float4 xpv = *reinterpret_cast<const float4*>(feat + (fbase + tp) * 128 + u0);

        f32x4 acc0 = {bias[0][0], bias[0][1], bias[0][2], bias[0][3]};
        f32x4 acc1 = {bias[1][0], bias[1][1], bias[1][2], bias[1][3]};
        f32x4 acc2 = {bias[2][0], bias[2][1], bias[2][2], bias[2][3]};
        f32x4 acc3 = {bias[3][0], bias[3][1], bias[3][2], bias[3][3]};

        const char* hrow = (const char*)&hx[cur][c][0];
        const u32x4* wp0 = &wlds[(wv * 2 + 0) * 8 * 64 + lane];
        const u32x4* wp1 = &wlds[(wv * 2 + 1) * 8 * 64 + lane];
#pragma unroll
        for (int ks = 0; ks < 8; ++ks) {
            u32x4 bq = *reinterpret_cast<const u32x4*>(
                hrow + ((ks * 64 + q * 16) ^ SWZ(c)));
            bf16x8 bf = __builtin_bit_cast(bf16x8, bq);
            acc0 = __builtin_amdgcn_mfma_f32_16x16x32_bf16(afr[0][ks], bf, acc0, 0, 0, 0);
            acc1 = __builtin_amdgcn_mfma_f32_16x16x32_bf16(afr[1][ks], bf, acc1, 0, 0, 0);
            bf16x8 a2 = __builtin_bit_cast(bf16x8, wp0[ks * 64]);
            acc2 = __builtin_amdgcn_mfma_f32_16x16x32_bf16(a2, bf, acc2, 0, 0, 0);
            bf16x8 a3 = __builtin_bit_cast(bf16x8, wp1[ks * 64]);
            acc3 = __builtin_amdgcn_mfma_f32_16x16x32_bf16(a3, bf, acc3, 0, 0, 0);
        }

        float h[4];
#pragma unroll
        for (int r = 0; r < 4; ++r) {
            float gi = sigf(acc0[r]);
            float gf = sigf(acc1[r]);
            float gg = tanhfast(acc2[r]);
            float go = sigf(acc3[r]);
            cst[r] = gf * cst[r] + gi * gg;
            h[r] = go * tanhfast(cst[r]);
        }
        *reinterpret_cast<float4*>(out + (fbase + t) * 128 + u0) =
            make_float4(h[0], h[1], h[2], h[3]);

        u32x4 u;
        u.x = (bfr(xpv.x) << 16) | bfr(h[0]);
        u.y = (bfr(xpv.y) << 16) | bfr(h[1]);
        u.z = (bfr(xpv.z) << 16) | bfr(h[2]);
        u.w = (bfr(xpv.w) << 16) | bfr(h[3]);
        *reinterpret_cast<u32x4*>((char*)&hx[cur ^ 1][c][0] + ((u0 * 4) ^ SWZ(c))) = u;

        cur ^= 1;
        __syncthreads();
    }
}

extern "C" void kernel_launch(void* const* d_in, const int* in_sizes, int n_in,
                              void* d_out, int out_size, void* d_ws, size_t ws_size,
                              hipStream_t stream)
{
    const float* x    = (const float*)d_in[0];
    const float* c1w  = (const float*)d_in[1];
    const float* bn1g = (const float*)d_in[2];
    const float* bn1b = (const float*)d_in[3];
    const float* bn1m = (const float*)d_in[4];
    const float* bn1v = (const float*)d_in[5];
    const float* c2w  = (const float*)d_in[6];
    const float* bn2g = (const float*)d_in[7];
    const float* bn2b = (const float*)d_in[8];
    const float* bn2m = (const float*)d_in[9];
    const float* bn2v = (const float*)d_in[10];
    const float* c3w  = (const float*)d_in[11];
    const float* bn3g = (const float*)d_in[12];
    const float* bn3b = (const float*)d_in[13];
    const float* bn3m = (const float*)d_in[14];
    const float* bn3v = (const float*)d_in[15];
    const float* w_ih = (const float*)d_in[16];
    const float* w_hh = (const float*)d_in[17];
    const float* b_ih = (const float*)d_in[18];
    const float* b_hh = (const float*)d_in[19];
    float* out = (float*)d_out;

    const int B = 64, T = 4096;
    char* ws = (char*)d_ws;
    const size_t sz_y1 = (size_t)B * 32 * T * 4;        //  32 MB
    const size_t sz_y2 = (size_t)B * 64 * T * 4;        //  64 MB
    const size_t sz_xp = (size_t)B * T * 512 * 2;       // 256 MB (f16)

    const bool fast = ws_size >= sz_y2 + sz_xp;         // 320 MB

    if (fast) {
        float* y1t   = (float*)d_out;            // d_out scratch (dead later)
        float* y2t   = (float*)ws;               // ws[0, 64MB), t-major
        float* feat  = (float*)d_out;            // d_out reused (y1t dead)
        _Float16* xp = (_Float16*)(ws + sz_y2);  // ws[64, 320MB)
        unsigned* apk  = (unsigned*)(ws + sz_y2);             // 112KB in xp region
        unsigned* apk2 = (unsigned*)(ws + sz_y2 + (1 << 20)); //  28KB in xp region
        unsigned* wpk  = (unsigned*)ws;          // 128KB over y2t head, AFTER conv3m

        k_pack_w2<<<dim3(7), 256, 0, stream>>>(c2w, bn2g, bn2v, apk2);
        k_pack_w3<<<dim3(28), 256, 0, stream>>>(c3w, bn3g, bn3v, apk);
        k_conv1t<<<dim3(T / 256, B), 256, 0, stream>>>(x, c1w, bn1g, bn1b, bn1m, bn1v, y1t, B, T);
        k_conv2m<<<dim3(T / 64, B), 256, 0, stream>>>(y1t, apk2, bn2g, bn2b, bn2m, bn2v, y2t, B, T);
        k_conv3m<<<dim3(T / 64, B), 512, 0, stream>>>(y2t, apk, bn3g, bn3b, bn3m, bn3v, feat, B, T);
        k_pack_wih<<<dim3(32), 256, 0, stream>>>(w_ih, wpk);
        k_xpre<<<dim3(T / 32, B), 256, 0, stream>>>(feat, wpk, b_ih, b_hh, xp, T);
        k_lstm8<<<dim3(8), 512, 0, stream>>>(xp, w_hh, out, T);
    } else {
        float* y1   = (float*)ws;
        float* y2t  = (float*)(ws + sz_y1);
        float* feat = (float*)(ws + sz_y1 + sz_y2);
        unsigned* apk = (unsigned*)ws;           // y1 region, dead after conv2

        k_conv1<<<dim3(T / 256, B), 256, 0, stream>>>(x, c1w, bn1g, bn1b, bn1m, bn1v, y1, B, T);
        k_conv2<<<dim3(T / 256, B), 256, 0, stream>>>(y1, c2w, bn2g, bn2b, bn2m, bn2v, y2t, B, T);
        k_pack_w3<<<dim3(28), 256, 0, stream>>>(c3w, bn3g, bn3v, apk);
        k_conv3m<<<dim3(T / 64, B), 512, 0, stream>>>(y2t, apk, bn3g, bn3b, bn3m, bn3v, feat, B, T);
        k_lstm4<<<dim3(4), 512, 0, stream>>>(feat, w_ih, w_hh, b_ih, b_hh, out, T);
    }
}

// Round 16
// 4070.665 us; speedup vs baseline: 1.0737x; 1.0737x over previous
//
#include <hip/hip_runtime.h>
#include <cstdint>
#include <cstddef>

#define BN_EPS 1e-5f
#define L2E   1.4426950408889634f
#define L2E2  2.8853900817779268f

typedef __attribute__((ext_vector_type(8))) short  bf16x8;
typedef __attribute__((ext_vector_type(4))) float  f32x4;
typedef __attribute__((ext_vector_type(4))) unsigned u32x4;
typedef __attribute__((ext_vector_type(2))) unsigned u32x2;
typedef __attribute__((ext_vector_type(8))) _Float16 f16x8;
typedef __attribute__((ext_vector_type(4))) _Float16 f16x4;

__device__ __forceinline__ float sigf(float x) {
    return 1.0f / (1.0f + __expf(-x));
}
__device__ __forceinline__ float tanhfast(float x) {
    return 2.0f / (1.0f + __expf(-2.0f * x)) - 1.0f;
}
__device__ __forceinline__ unsigned bfr(float x) {  // f32 -> bf16 bits (RNE)
    unsigned u = __float_as_uint(x);
    return (u + 0x7fffu + ((u >> 16) & 1u)) >> 16;
}
__device__ __forceinline__ bf16x8 pack8(float4 a, float4 b) {  // ascending k
    u32x4 u;
    u.x = (bfr(a.y) << 16) | bfr(a.x);
    u.y = (bfr(a.w) << 16) | bfr(a.z);
    u.z = (bfr(b.y) << 16) | bfr(b.x);
    u.w = (bfr(b.w) << 16) | bfr(b.z);
    return __builtin_bit_cast(bf16x8, u);
}
__device__ __forceinline__ float rcp_f(float x) {
    return __builtin_amdgcn_rcpf(x);
}
__device__ __forceinline__ float exp2_f(float x) {
    return __builtin_amdgcn_exp2f(x);
}
__device__ __forceinline__ unsigned cvtpk_bf16(float lo, float hi) {
    unsigned r; asm("v_cvt_pk_bf16_f32 %0, %1, %2" : "=v"(r) : "v"(lo), "v"(hi));
    return r;
}

// LDS-only barrier: global loads/stores stay in flight across steps.
#define LBAR()                                                   \
    do {                                                         \
        asm volatile("s_waitcnt lgkmcnt(0)" ::: "memory");       \
        __builtin_amdgcn_s_barrier();                            \
        asm volatile("" ::: "memory");                           \
    } while (0)

// ---------------- conv1 (fallback, channel-major y1[B,32,T]) ----------------
__global__ __launch_bounds__(256) void k_conv1(
    const float* __restrict__ x, const float* __restrict__ w,
    const float* __restrict__ g, const float* __restrict__ bb,
    const float* __restrict__ m, const float* __restrict__ v,
    float* __restrict__ y1, int B, int T)
{
    const int TT = 256;
    __shared__ float xs[(TT + 6) * 9];
    const int b = blockIdx.y;
    const int t0 = blockIdx.x * TT;
    const int tid = threadIdx.x;

    for (int idx = tid; idx < (TT + 6) * 9; idx += 256) {
        int row = idx / 9, col = idx - row * 9;
        int tg = t0 - 3 + row;
        xs[idx] = (tg >= 0 && tg < T) ? x[((size_t)b * T + tg) * 9 + col] : 0.0f;
    }
    __syncthreads();

    float xv[63];
#pragma unroll
    for (int k = 0; k < 7; ++k)
#pragma unroll
        for (int ci = 0; ci < 9; ++ci)
            xv[k * 9 + ci] = xs[(tid + k) * 9 + ci];

    const int t = t0 + tid;
    for (int co = 0; co < 32; ++co) {
        float acc = 0.0f;
#pragma unroll
        for (int ci = 0; ci < 9; ++ci)
#pragma unroll
            for (int k = 0; k < 7; ++k)
                acc += xv[k * 9 + ci] * w[(co * 9 + ci) * 7 + k];
        float sc = g[co] / sqrtf(v[co] + BN_EPS);
        float bf = bb[co] - m[co] * sc;
        float o = acc * sc + bf;
        y1[((size_t)b * 32 + co) * T + t] = o > 0.0f ? o : 0.0f;
    }
}

// ---------------- conv1 (fast path, t-major y1t[B,T,32]) --------------------
__global__ __launch_bounds__(256) void k_conv1t(
    const float* __restrict__ x, const float* __restrict__ w,
    const float* __restrict__ g, const float* __restrict__ bb,
    const float* __restrict__ m, const float* __restrict__ v,
    float* __restrict__ y1t, int B, int T)
{
    const int TT = 256;
    __shared__ float xs[(TT + 6) * 9];
    const int b = blockIdx.y;
    const int t0 = blockIdx.x * TT;
    const int tid = threadIdx.x;

    for (int idx = tid; idx < (TT + 6) * 9; idx += 256) {
        int row = idx / 9, col = idx - row * 9;
        int tg = t0 - 3 + row;
        xs[idx] = (tg >= 0 && tg < T) ? x[((size_t)b * T + tg) * 9 + col] : 0.0f;
    }
    __syncthreads();

    float xv[63];
#pragma unroll
    for (int k = 0; k < 7; ++k)
#pragma unroll
        for (int ci = 0; ci < 9; ++ci)
            xv[k * 9 + ci] = xs[(tid + k) * 9 + ci];

    const int t = t0 + tid;
    float* orow = y1t + ((size_t)b * T + t) * 32;
    for (int co = 0; co < 32; ++co) {
        float acc = 0.0f;
#pragma unroll
        for (int ci = 0; ci < 9; ++ci)
#pragma unroll
            for (int k = 0; k < 7; ++k)
                acc += xv[k * 9 + ci] * w[(co * 9 + ci) * 7 + k];
        float sc = g[co] / sqrtf(v[co] + BN_EPS);
        float bf = bb[co] - m[co] * sc;
        float o = acc * sc + bf;
        orow[co] = o > 0.0f ? o : 0.0f;
    }
}

// -------- conv2 (fallback, scalar): y1[B,32,T] -> y2t[B,T,64] ---------------
__global__ __launch_bounds__(256) void k_conv2(
    const float* __restrict__ y1, const float* __restrict__ w,
    const float* __restrict__ g, const float* __restrict__ bb,
    const float* __restrict__ m, const float* __restrict__ v,
    float* __restrict__ y2t, int B, int T)
{
    const int TT = 256;
    __shared__ float ys[32 * (TT + 6)];
    const int b = blockIdx.y;
    const int t0 = blockIdx.x * TT;
    const int tid = threadIdx.x;

    for (int idx = tid; idx < 32 * (TT + 6); idx += 256) {
        int ci = idx / (TT + 6), i = idx - ci * (TT + 6);
        int tg = t0 - 3 + i;
        ys[idx] = (tg >= 0 && tg < T) ? y1[((size_t)b * 32 + ci) * T + tg] : 0.0f;
    }
    __syncthreads();

    float acc[64];
#pragma unroll
    for (int co = 0; co < 64; ++co) acc[co] = 0.0f;

    for (int ci = 0; ci < 32; ++ci) {
        float yw[7];
#pragma unroll
        for (int k = 0; k < 7; ++k) yw[k] = ys[ci * (TT + 6) + tid + k];
#pragma unroll
        for (int co = 0; co < 64; ++co)
#pragma unroll
            for (int k = 0; k < 7; ++k)
                acc[co] += yw[k] * w[(co * 32 + ci) * 7 + k];
    }

    const int t = t0 + tid;
    float* orow = y2t + ((size_t)b * T + t) * 64;
    for (int co = 0; co < 64; co += 4) {
        float4 o;
        float s0 = g[co+0] / sqrtf(v[co+0] + BN_EPS);
        float s1 = g[co+1] / sqrtf(v[co+1] + BN_EPS);
        float s2 = g[co+2] / sqrtf(v[co+2] + BN_EPS);
        float s3 = g[co+3] / sqrtf(v[co+3] + BN_EPS);
        o.x = acc[co+0] * s0 + (bb[co+0] - m[co+0] * s0);
        o.y = acc[co+1] * s1 + (bb[co+1] - m[co+1] * s1);
        o.z = acc[co+2] * s2 + (bb[co+2] - m[co+2] * s2);
        o.w = acc[co+3] * s3 + (bb[co+3] - m[co+3] * s3);
        o.x = o.x > 0.f ? o.x : 0.f;
        o.y = o.y > 0.f ? o.y : 0.f;
        o.z = o.z > 0.f ? o.z : 0.f;
        o.w = o.w > 0.f ? o.w : 0.f;
        *reinterpret_cast<float4*>(orow + co) = o;
    }
}

// ---- pack conv2 weights -> bf16 frag order, BN scale folded (1792 tuples) --
__global__ __launch_bounds__(256) void k_pack_w2(
    const float* __restrict__ w2, const float* __restrict__ g,
    const float* __restrict__ v, unsigned* __restrict__ apk2)
{
    int tu = blockIdx.x * 256 + threadIdx.x;
    if (tu >= 4 * 7 * 64) return;
    int lane = tu & 63, kk = (tu >> 6) % 7, rt = tu / (7 * 64);
    int c = lane & 15, q = lane >> 4;
    int co = rt * 16 + c, ci0 = q * 8;
    float sc = g[co] / sqrtf(v[co] + BN_EPS);
    float4 a, b;
    a.x = w2[(co * 32 + ci0 + 0) * 7 + kk] * sc;
    a.y = w2[(co * 32 + ci0 + 1) * 7 + kk] * sc;
    a.z = w2[(co * 32 + ci0 + 2) * 7 + kk] * sc;
    a.w = w2[(co * 32 + ci0 + 3) * 7 + kk] * sc;
    b.x = w2[(co * 32 + ci0 + 4) * 7 + kk] * sc;
    b.y = w2[(co * 32 + ci0 + 5) * 7 + kk] * sc;
    b.z = w2[(co * 32 + ci0 + 6) * 7 + kk] * sc;
    b.w = w2[(co * 32 + ci0 + 7) * 7 + kk] * sc;
    bf16x8 p = pack8(a, b);
    *reinterpret_cast<u32x4*>(apk2 + (size_t)tu * 4) = __builtin_bit_cast(u32x4, p);
}

// --------- conv2 via MFMA : y1t[B,T,32] -> y2t[B,T,64] ----------------------
__global__ __launch_bounds__(256) void k_conv2m(
    const float* __restrict__ y1t, const unsigned* __restrict__ apk2,
    const float* __restrict__ g, const float* __restrict__ bb,
    const float* __restrict__ m, const float* __restrict__ v,
    float* __restrict__ y2t, int B, int T)
{
    __shared__ __align__(16) unsigned short yst[70 * 40];  // bf16, 5.6 KB
    const int b  = blockIdx.y;
    const int t0 = blockIdx.x * 64;
    const int tid = threadIdx.x;
    const int wv = tid >> 6;            // row-tile
    const int lane = tid & 63;
    const int c = lane & 15, q = lane >> 4;

    for (int i = tid; i < 70 * 4; i += 256) {
        int row = i >> 2, cg = (i & 3) * 8;
        int tg = t0 - 3 + row;
        bf16x8 p;
        if (tg >= 0 && tg < T) {
            const float* src = y1t + ((size_t)b * T + tg) * 32 + cg;
            float4 a0 = *reinterpret_cast<const float4*>(src);
            float4 a1 = *reinterpret_cast<const float4*>(src + 4);
            p = pack8(a0, a1);
        } else {
            u32x4 z = {0u, 0u, 0u, 0u};
            p = __builtin_bit_cast(bf16x8, z);
        }
        *reinterpret_cast<u32x4*>(&yst[row * 40 + cg]) = __builtin_bit_cast(u32x4, p);
    }
    __syncthreads();

    f32x4 acc[4] = {{0,0,0,0},{0,0,0,0},{0,0,0,0},{0,0,0,0}};
#pragma unroll
    for (int kk = 0; kk < 7; ++kk) {
        u32x4 au = *reinterpret_cast<const u32x4*>(
            apk2 + ((size_t)(wv * 7 + kk) * 64 + lane) * 4);
        bf16x8 av = __builtin_bit_cast(bf16x8, au);
#pragma unroll
        for (int nt = 0; nt < 4; ++nt) {
            u32x4 bu = *reinterpret_cast<const u32x4*>(
                &yst[(nt * 16 + c + kk) * 40 + q * 8]);
            bf16x8 bv = __builtin_bit_cast(bf16x8, bu);
            acc[nt] = __builtin_amdgcn_mfma_f32_16x16x32_bf16(av, bv, acc[nt], 0, 0, 0);
        }
    }

    const int co0 = wv * 16 + q * 4;
    float bf4[4];
#pragma unroll
    for (int r = 0; r < 4; ++r) {
        float sc = g[co0 + r] / sqrtf(v[co0 + r] + BN_EPS);
        bf4[r] = bb[co0 + r] - m[co0 + r] * sc;
    }
#pragma unroll
    for (int nt = 0; nt < 4; ++nt) {
        const int t = t0 + nt * 16 + c;
        float4 o;
        o.x = acc[nt][0] + bf4[0]; o.x = o.x > 0.f ? o.x : 0.f;
        o.y = acc[nt][1] + bf4[1]; o.y = o.y > 0.f ? o.y : 0.f;
        o.z = acc[nt][2] + bf4[2]; o.z = o.z > 0.f ? o.z : 0.f;
        o.w = acc[nt][3] + bf4[3]; o.w = o.w > 0.f ? o.w : 0.f;
        *reinterpret_cast<float4*>(y2t + ((size_t)b * T + t) * 64 + co0) = o;
    }
}

// ---- pack conv3 weights -> bf16 frag order, BN scale folded (7168 tuples) --
__global__ __launch_bounds__(256) void k_pack_w3(
    const float* __restrict__ w3, const float* __restrict__ g,
    const float* __restrict__ v, unsigned* __restrict__ apk)
{
    int tu = blockIdx.x * 256 + threadIdx.x;
    if (tu >= 8 * 14 * 64) return;
    int lane = tu & 63, ks = (tu >> 6) % 14, rt = tu / (14 * 64);
    int c = lane & 15, q = lane >> 4;
    int co = rt * 16 + c, kk = ks >> 1, ci0 = (ks & 1) * 32 + q * 8;
    float sc = g[co] / sqrtf(v[co] + BN_EPS);
    float4 a, b;
    a.x = w3[(co * 64 + ci0 + 0) * 7 + kk] * sc;
    a.y = w3[(co * 64 + ci0 + 1) * 7 + kk] * sc;
    a.z = w3[(co * 64 + ci0 + 2) * 7 + kk] * sc;
    a.w = w3[(co * 64 + ci0 + 3) * 7 + kk] * sc;
    b.x = w3[(co * 64 + ci0 + 4) * 7 + kk] * sc;
    b.y = w3[(co * 64 + ci0 + 5) * 7 + kk] * sc;
    b.z = w3[(co * 64 + ci0 + 6) * 7 + kk] * sc;
    b.w = w3[(co * 64 + ci0 + 7) * 7 + kk] * sc;
    bf16x8 p = pack8(a, b);
    *reinterpret_cast<u32x4*>(apk + (size_t)tu * 4) = __builtin_bit_cast(u32x4, p);
}

// ---- pack W_ih -> bf16 frag order, gate exp2-scales folded (8192 tuples) ---
__global__ __launch_bounds__(256) void k_pack_wih(
    const float* __restrict__ w_ih, unsigned* __restrict__ wpk)
{
    int tu = blockIdx.x * 256 + threadIdx.x;
    if (tu >= 4 * 8 * 4 * 64) return;
    int lane = tu & 63, ks = (tu >> 6) & 3, rt = (tu >> 8) & 7, gg = tu >> 11;
    int c = lane & 15, q = lane >> 4;
    int row = gg * 128 + rt * 16 + c;
    float sc = (gg == 2) ? L2E2 : -L2E;
    const float* src = w_ih + (size_t)row * 128 + ks * 32 + q * 8;
    float4 a = *reinterpret_cast<const float4*>(src);
    float4 b = *reinterpret_cast<const float4*>(src + 4);
    a.x *= sc; a.y *= sc; a.z *= sc; a.w *= sc;
    b.x *= sc; b.y *= sc; b.z *= sc; b.w *= sc;
    bf16x8 p = pack8(a, b);
    *reinterpret_cast<u32x4*>(wpk + (size_t)tu * 4) = __builtin_bit_cast(u32x4, p);
}

// ------------- conv3 via MFMA : y2t[B,T,64] -> feat[B,T,128] ----------------
__global__ __launch_bounds__(512) void k_conv3m(
    const float* __restrict__ y2t, const unsigned* __restrict__ apk,
    const float* __restrict__ g, const float* __restrict__ bb,
    const float* __restrict__ m, const float* __restrict__ v,
    float* __restrict__ feat, int B, int T)
{
    __shared__ __align__(16) unsigned short yst[70 * 72];  // bf16, 9.8 KB
    const int b  = blockIdx.y;
    const int t0 = blockIdx.x * 64;
    const int tid = threadIdx.x;
    const int wv = tid >> 6;            // row-tile
    const int lane = tid & 63;
    const int c = lane & 15, q = lane >> 4;

    for (int i = tid; i < 70 * 8; i += 512) {
        int row = i >> 3, cg = (i & 7) * 8;
        int tg = t0 - 3 + row;
        bf16x8 p;
        if (tg >= 0 && tg < T) {
            const float* src = y2t + ((size_t)b * T + tg) * 64 + cg;
            float4 a0 = *reinterpret_cast<const float4*>(src);
            float4 a1 = *reinterpret_cast<const float4*>(src + 4);
            p = pack8(a0, a1);
        } else {
            u32x4 z = {0u, 0u, 0u, 0u};
            p = __builtin_bit_cast(bf16x8, z);
        }
        *reinterpret_cast<u32x4*>(&yst[row * 72 + cg]) = __builtin_bit_cast(u32x4, p);
    }
    __syncthreads();

    f32x4 acc[4] = {{0,0,0,0},{0,0,0,0},{0,0,0,0},{0,0,0,0}};
#pragma unroll
    for (int ks = 0; ks < 14; ++ks) {
        const int kk = ks >> 1, ci0 = (ks & 1) * 32 + q * 8;
        u32x4 au = *reinterpret_cast<const u32x4*>(
            apk + ((size_t)(wv * 14 + ks) * 64 + lane) * 4);
        bf16x8 av = __builtin_bit_cast(bf16x8, au);
#pragma unroll
        for (int nt = 0; nt < 4; ++nt) {
            u32x4 bu = *reinterpret_cast<const u32x4*>(
                &yst[(nt * 16 + c + kk) * 72 + ci0]);
            bf16x8 bv = __builtin_bit_cast(bf16x8, bu);
            acc[nt] = __builtin_amdgcn_mfma_f32_16x16x32_bf16(av, bv, acc[nt], 0, 0, 0);
        }
    }

    const int co0 = wv * 16 + q * 4;
    float bf4[4];
#pragma unroll
    for (int r = 0; r < 4; ++r) {
        float sc = g[co0 + r] / sqrtf(v[co0 + r] + BN_EPS);
        bf4[r] = bb[co0 + r] - m[co0 + r] * sc;
    }
#pragma unroll
    for (int nt = 0; nt < 4; ++nt) {
        const int t = t0 + nt * 16 + c;
        float4 o;
        o.x = acc[nt][0] + bf4[0]; o.x = o.x > 0.f ? o.x : 0.f;
        o.y = acc[nt][1] + bf4[1]; o.y = o.y > 0.f ? o.y : 0.f;
        o.z = acc[nt][2] + bf4[2]; o.z = o.z > 0.f ? o.z : 0.f;
        o.w = acc[nt][3] + bf4[3]; o.w = o.w > 0.f ? o.w : 0.f;
        *reinterpret_cast<float4*>(feat + ((size_t)b * T + t) * 128 + co0) = o;
    }
}

// ----------- x-projection GEMM: xp = scale_g*(W_ih·x + b) (f16) -------------
__global__ __launch_bounds__(256) void k_xpre(
    const float* __restrict__ feat, const unsigned* __restrict__ wpk,
    const float* __restrict__ b_ih, const float* __restrict__ b_hh,
    _Float16* __restrict__ xp, int T)
{
    const int b   = blockIdx.y;
    const int t0  = blockIdx.x * 32;
    const int tid = threadIdx.x;
    const int wv2 = tid >> 6;      // gate g
    const int lane = tid & 63;
    const int c2 = lane & 15;
    const int q2 = lane >> 4;
    const float sc = (wv2 == 2) ? L2E2 : -L2E;

    bf16x8 btile[2][4];
#pragma unroll
    for (int tc = 0; tc < 2; ++tc) {
        const float* xrow = feat + ((size_t)b * T + t0 + tc * 16 + c2) * 128;
#pragma unroll
        for (int ks = 0; ks < 4; ++ks) {
            float4 x0 = *reinterpret_cast<const float4*>(xrow + ks * 32 + q2 * 8);
            float4 x1 = *reinterpret_cast<const float4*>(xrow + ks * 32 + q2 * 8 + 4);
            btile[tc][ks] = pack8(x0, x1);
        }
    }

#pragma unroll
    for (int rt = 0; rt < 8; ++rt) {
        bf16x8 a[4];
#pragma unroll
        for (int ks = 0; ks < 4; ++ks) {
            u32x4 au = *reinterpret_cast<const u32x4*>(
                wpk + ((size_t)(((wv2 * 8 + rt) * 4 + ks) * 64) + lane) * 4);
            a[ks] = __builtin_bit_cast(bf16x8, au);
        }
        const int gr0 = wv2 * 128 + rt * 16 + q2 * 4;
        float4 bi = *reinterpret_cast<const float4*>(b_ih + gr0);
        float4 bh = *reinterpret_cast<const float4*>(b_hh + gr0);
        f32x4 bias = {(bi.x + bh.x) * sc, (bi.y + bh.y) * sc,
                      (bi.z + bh.z) * sc, (bi.w + bh.w) * sc};

#pragma unroll
        for (int tc = 0; tc < 2; ++tc) {
            f32x4 acc = bias;
#pragma unroll
            for (int ks = 0; ks < 4; ++ks)
                acc = __builtin_amdgcn_mfma_f32_16x16x32_bf16(a[ks], btile[tc][ks], acc, 0, 0, 0);
            const int t = t0 + tc * 16 + c2;
            f16x4 hv = {(_Float16)acc[0], (_Float16)acc[1],
                        (_Float16)acc[2], (_Float16)acc[3]};
            *reinterpret_cast<f16x4*>(
                xp + ((size_t)b * T + t) * 512 + (rt * 4 + q2) * 16 + wv2 * 4) = hv;
        }
    }
}

// --------------------- reversed-time LSTM (MFMA, K=128) ---------------------
// R14's proven k_lstm7 body, verbatim (R15's trans-fusion + ptr-walk REGRESSED
// 3.68 -> 3.99 ms: the fused rcp((1+eI)(1+eG)) and fminf lengthened the serial
// cst dependency chain — this kernel is latency-bound, not issue-bound).
#define SWZ(b) (((b) & 7) << 4)

#define LSTM_BODY(TCUR, RBUF, WBUF, Q0, Q1, PFT)                              \
    {                                                                          \
        f32x4 acc0 = {(float)Q0[0], (float)Q0[1], (float)Q0[2], (float)Q0[3]}; \
        f32x4 acc1 = {(float)Q0[4], (float)Q0[5], (float)Q0[6], (float)Q0[7]}; \
        f32x4 acc2 = {(float)Q1[0], (float)Q1[1], (float)Q1[2], (float)Q1[3]}; \
        f32x4 acc3 = {(float)Q1[4], (float)Q1[5], (float)Q1[6], (float)Q1[7]}; \
        const int pt_ = ((PFT) >= 0) ? (PFT) : 0;                              \
        Q0 = *reinterpret_cast<const f16x8*>(xpb + (size_t)pt_ * 512);         \
        Q1 = *reinterpret_cast<const f16x8*>(xpb + (size_t)pt_ * 512 + 8);     \
        const char* hrow_ = (const char*)&RBUF[c][0];                          \
        _Pragma("unroll")                                                      \
        for (int ks = 0; ks < 4; ++ks) {                                       \
            u32x4 bq = *reinterpret_cast<const u32x4*>(                        \
                hrow_ + ((ks * 64 + q * 16) ^ SWZ(c)));                        \
            bf16x8 bf = __builtin_bit_cast(bf16x8, bq);                        \
            acc0 = __builtin_amdgcn_mfma_f32_16x16x32_bf16(afr[0][ks], bf, acc0, 0, 0, 0); \
            acc1 = __builtin_amdgcn_mfma_f32_16x16x32_bf16(afr[1][ks], bf, acc1, 0, 0, 0); \
            acc2 = __builtin_amdgcn_mfma_f32_16x16x32_bf16(afr[2][ks], bf, acc2, 0, 0, 0); \
            acc3 = __builtin_amdgcn_mfma_f32_16x16x32_bf16(afr[3][ks], bf, acc3, 0, 0, 0); \
        }                                                                      \
        float h4_[4];                                                          \
        _Pragma("unroll")                                                      \
        for (int r = 0; r < 4; ++r) {                                          \
            float gi = rcp_f(1.0f + exp2_f(acc0[r]));                          \
            float gf = rcp_f(1.0f + exp2_f(acc1[r]));                          \
            float gg = fmaf(-2.0f, rcp_f(1.0f + exp2_f(acc2[r])), 1.0f);       \
            float go = rcp_f(1.0f + exp2_f(acc3[r]));                          \
            cst[r] = fmaf(gf, cst[r], gi * gg);                                \
            float tc_ = fmaf(-2.0f, rcp_f(1.0f + exp2_f(cst[r] * L2E2)), 1.0f);\
            h4_[r] = go * tc_;                                                 \
        }                                                                      \
        if (valid) {                                                           \
            *reinterpret_cast<float4*>(out + ((size_t)b * T + (TCUR)) * 128 + u0) = \
                make_float4(h4_[0], h4_[1], h4_[2], h4_[3]);                   \
            u32x2 hw_;                                                         \
            hw_.x = cvtpk_bf16(h4_[0], h4_[1]);                                \
            hw_.y = cvtpk_bf16(h4_[2], h4_[3]);                                \
            *reinterpret_cast<u32x2*>(                                         \
                (char*)&WBUF[c][0] + ((u0 * 2) ^ SWZ(c))) = hw_;               \
        }                                                                      \
    }

__global__ __launch_bounds__(512) void k_lstm7(
    const _Float16* __restrict__ xp, const float* __restrict__ w_hh,
    float* __restrict__ out, int T)
{
    __shared__ __align__(16) unsigned short h_lds[2][16][128];  // bf16, 8 KB

    const int tid  = threadIdx.x;
    const int bk   = blockIdx.x;          // batches [bk*8, bk*8+8)
    const int wv   = tid >> 6;
    const int lane = tid & 63;
    const int c    = lane & 15;
    const int q    = lane >> 4;
    const int u0   = wv * 16 + q * 4;
    const bool valid = (c < 8);
    const int b    = bk * 8 + (c & 7);    // clamped for invalid lanes

    bf16x8 afr[4][4];
#pragma unroll
    for (int g = 0; g < 4; ++g) {
        const float sc = (g == 2) ? L2E2 : -L2E;
        const float* wr = w_hh + (size_t)(g * 128 + wv * 16 + c) * 128;
#pragma unroll
        for (int ks = 0; ks < 4; ++ks) {
            float4 w0 = *reinterpret_cast<const float4*>(wr + ks * 32 + q * 8);
            float4 w1 = *reinterpret_cast<const float4*>(wr + ks * 32 + q * 8 + 4);
            w0.x *= sc; w0.y *= sc; w0.z *= sc; w0.w *= sc;
            w1.x *= sc; w1.y *= sc; w1.z *= sc; w1.w *= sc;
            afr[g][ks] = pack8(w0, w1);
        }
    }

    {
        u32x2 z = {0u, 0u};
        *reinterpret_cast<u32x2*>((char*)&h_lds[0][c][0] + ((u0 * 2) ^ SWZ(c))) = z;
        *reinterpret_cast<u32x2*>((char*)&h_lds[1][c][0] + ((u0 * 2) ^ SWZ(c))) = z;
    }
    f32x4 cst = {0.f, 0.f, 0.f, 0.f};

    const _Float16* xpb = xp + ((size_t)b * T) * 512 + (wv * 4 + q) * 16;
    f16x8 PA0 = *reinterpret_cast<const f16x8*>(xpb + (size_t)(T - 1) * 512);
    f16x8 PA1 = *reinterpret_cast<const f16x8*>(xpb + (size_t)(T - 1) * 512 + 8);
    f16x8 PB0 = *reinterpret_cast<const f16x8*>(xpb + (size_t)(T - 2) * 512);
    f16x8 PB1 = *reinterpret_cast<const f16x8*>(xpb + (size_t)(T - 2) * 512 + 8);
    __syncthreads();

    for (int t = T - 1; t > 0; t -= 2) {
        LSTM_BODY(t,     h_lds[0], h_lds[1], PA0, PA1, t - 2);
        LBAR();
        LSTM_BODY(t - 1, h_lds[1], h_lds[0], PB0, PB1, t - 3);
        LBAR();
    }
}

// ------------------- fallback LSTM (K=256 interleaved) ----------------------
__global__ __launch_bounds__(512) void k_lstm4(
    const float* __restrict__ feat, const float* __restrict__ w_ih,
    const float* __restrict__ w_hh, const float* __restrict__ b_ih,
    const float* __restrict__ b_hh, float* __restrict__ out, int T)
{
    __shared__ __align__(16) unsigned hx[2][16][128];
    __shared__ __align__(16) u32x4 wlds[8 * 2 * 8 * 64];

    const int tid  = threadIdx.x;
    const int bk   = blockIdx.x;
    const int wv   = tid >> 6;
    const int lane = tid & 63;
    const int c    = lane & 15;
    const int q    = lane >> 4;

    bf16x8 afr[2][8];
#pragma unroll
    for (int g = 0; g < 4; ++g) {
        const int row = g * 128 + wv * 16 + c;
#pragma unroll
        for (int ks = 0; ks < 8; ++ks) {
            const int m0 = ks * 16 + q * 4;
            float4 h4 = *reinterpret_cast<const float4*>(w_hh + (size_t)row * 128 + m0);
            float4 i4 = *reinterpret_cast<const float4*>(w_ih + (size_t)row * 128 + m0);
            u32x4 u;
            u.x = (bfr(i4.x) << 16) | bfr(h4.x);
            u.y = (bfr(i4.y) << 16) | bfr(h4.y);
            u.z = (bfr(i4.z) << 16) | bfr(h4.z);
            u.w = (bfr(i4.w) << 16) | bfr(h4.w);
            if (g < 2)
                afr[g][ks] = __builtin_bit_cast(bf16x8, u);
            else
                wlds[((wv * 2 + (g - 2)) * 8 + ks) * 64 + lane] = u;
        }
    }

    float bias[4][4];
#pragma unroll
    for (int g = 0; g < 4; ++g)
#pragma unroll
        for (int r = 0; r < 4; ++r) {
            const int j = wv * 16 + q * 4 + r;
            bias[g][r] = b_ih[g * 128 + j] + b_hh[g * 128 + j];
        }

    const size_t fbase = ((size_t)(bk * 16 + c)) * T;
    const int u0 = wv * 16 + q * 4;

    {
        float4 x0 = *reinterpret_cast<const float4*>(feat + (fbase + (T - 1)) * 128 + u0);
        u32x4 u;
        u.x = bfr(x0.x) << 16;
        u.y = bfr(x0.y) << 16;
        u.z = bfr(x0.z) << 16;
        u.w = bfr(x0.w) << 16;
        *reinterpret_cast<u32x4*>((char*)&hx[0][c][0] + ((u0 * 4) ^ SWZ(c))) = u;
    }
    f32x4 cst = {0.f, 0.f, 0.f, 0.f};
    __syncthreads();

    int cur = 0;
    for (int t = T - 1; t >= 0; --t) {
        const int tp = (t > 0) ? t - 1 : 0;
        float4 xpv = *reinterpret_cast<const float4*>(feat + (fbase + tp) * 128 + u0);

        f32x4 acc0 = {bias[0][0], bias[0][1], bias[0][2], bias[0][3]};
        f32x4 acc1 = {bias[1][0], bias[1][1], bias[1][2], bias[1][3]};
        f32x4 acc2 = {bias[2][0], bias[2][1], bias[2][2], bias[2][3]};
        f32x4 acc3 = {bias[3][0], bias[3][1], bias[3][2], bias[3][3]};

        const char* hrow = (const char*)&hx[cur][c][0];
        const u32x4* wp0 = &wlds[(wv * 2 + 0) * 8 * 64 + lane];
        const u32x4* wp1 = &wlds[(wv * 2 + 1) * 8 * 64 + lane];
#pragma unroll
        for (int ks = 0; ks < 8; ++ks) {
            u32x4 bq = *reinterpret_cast<const u32x4*>(
                hrow + ((ks * 64 + q * 16) ^ SWZ(c)));
            bf16x8 bf = __builtin_bit_cast(bf16x8, bq);
            acc0 = __builtin_amdgcn_mfma_f32_16x16x32_bf16(afr[0][ks], bf, acc0, 0, 0, 0);
            acc1 = __builtin_amdgcn_mfma_f32_16x16x32_bf16(afr[1][ks], bf, acc1, 0, 0, 0);
            bf16x8 a2 = __builtin_bit_cast(bf16x8, wp0[ks * 64]);
            acc2 = __builtin_amdgcn_mfma_f32_16x16x32_bf16(a2, bf, acc2, 0, 0, 0);
            bf16x8 a3 = __builtin_bit_cast(bf16x8, wp1[ks * 64]);
            acc3 = __builtin_amdgcn_mfma_f32_16x16x32_bf16(a3, bf, acc3, 0, 0, 0);
        }

        float h[4];
#pragma unroll
        for (int r = 0; r < 4; ++r) {
            float gi = sigf(acc0[r]);
            float gf = sigf(acc1[r]);
            float gg = tanhfast(acc2[r]);
            float go = sigf(acc3[r]);
            cst[r] = gf * cst[r] + gi * gg;
            h[r] = go * tanhfast(cst[r]);
        }
        *reinterpret_cast<float4*>(out + (fbase + t) * 128 + u0) =
            make_float4(h[0], h[1], h[2], h[3]);

        u32x4 u;
        u.x = (bfr(xpv.x) << 16) | bfr(h[0]);
        u.y = (bfr(xpv.y) << 16) | bfr(h[1]);
        u.z = (bfr(xpv.z) << 16) | bfr(h[2]);
        u.w = (bfr(xpv.w) << 16) | bfr(h[3]);
        *reinterpret_cast<u32x4*>((char*)&hx[cur ^ 1][c][0] + ((u0 * 4) ^ SWZ(c))) = u;

        cur ^= 1;
        __syncthreads();
    }
}

extern "C" void kernel_launch(void* const* d_in, const int* in_sizes, int n_in,
                              void* d_out, int out_size, void* d_ws, size_t ws_size,
                              hipStream_t stream)
{
    const float* x    = (const float*)d_in[0];
    const float* c1w  = (const float*)d_in[1];
    const float* bn1g = (const float*)d_in[2];
    const float* bn1b = (const float*)d_in[3];
    const float* bn1m = (const float*)d_in[4];
    const float* bn1v = (const float*)d_in[5];
    const float* c2w  = (const float*)d_in[6];
    const float* bn2g = (const float*)d_in[7];
    const float* bn2b = (const float*)d_in[8];
    const float* bn2m = (const float*)d_in[9];
    const float* bn2v = (const float*)d_in[10];
    const float* c3w  = (const float*)d_in[11];
    const float* bn3g = (const float*)d_in[12];
    const float* bn3b = (const float*)d_in[13];
    const float* bn3m = (const float*)d_in[14];
    const float* bn3v = (const float*)d_in[15];
    const float* w_ih = (const float*)d_in[16];
    const float* w_hh = (const float*)d_in[17];
    const float* b_ih = (const float*)d_in[18];
    const float* b_hh = (const float*)d_in[19];
    float* out = (float*)d_out;

    const int B = 64, T = 4096;
    char* ws = (char*)d_ws;
    const size_t sz_y1 = (size_t)B * 32 * T * 4;        //  32 MB
    const size_t sz_y2 = (size_t)B * 64 * T * 4;        //  64 MB
    const size_t sz_xp = (size_t)B * T * 512 * 2;       // 256 MB (f16)

    const bool fast = ws_size >= sz_y2 + sz_xp;         // 320 MB

    if (fast) {
        float* y1t   = (float*)d_out;            // d_out scratch (dead later)
        float* y2t   = (float*)ws;               // ws[0, 64MB), t-major
        float* feat  = (float*)d_out;            // d_out reused (y1t dead)
        _Float16* xp = (_Float16*)(ws + sz_y2);  // ws[64, 320MB)
        unsigned* apk  = (unsigned*)(ws + sz_y2);             // 112KB in xp region
        unsigned* apk2 = (unsigned*)(ws + sz_y2 + (1 << 20)); //  28KB in xp region
        unsigned* wpk  = (unsigned*)ws;          // 128KB over y2t head, AFTER conv3m

        k_pack_w2<<<dim3(7), 256, 0, stream>>>(c2w, bn2g, bn2v, apk2);
        k_pack_w3<<<dim3(28), 256, 0, stream>>>(c3w, bn3g, bn3v, apk);
        k_conv1t<<<dim3(T / 256, B), 256, 0, stream>>>(x, c1w, bn1g, bn1b, bn1m, bn1v, y1t, B, T);
        k_conv2m<<<dim3(T / 64, B), 256, 0, stream>>>(y1t, apk2, bn2g, bn2b, bn2m, bn2v, y2t, B, T);
        k_conv3m<<<dim3(T / 64, B), 512, 0, stream>>>(y2t, apk, bn3g, bn3b, bn3m, bn3v, feat, B, T);
        k_pack_wih<<<dim3(32), 256, 0, stream>>>(w_ih, wpk);
        k_xpre<<<dim3(T / 32, B), 256, 0, stream>>>(feat, wpk, b_ih, b_hh, xp, T);
        k_lstm7<<<dim3(8), 512, 0, stream>>>(xp, w_hh, out, T);
    } else {
        float* y1   = (float*)ws;
        float* y2t  = (float*)(ws + sz_y1);
        float* feat = (float*)(ws + sz_y1 + sz_y2);
        unsigned* apk = (unsigned*)ws;           // y1 region, dead after conv2

        k_conv1<<<dim3(T / 256, B), 256, 0, stream>>>(x, c1w, bn1g, bn1b, bn1m, bn1v, y1, B, T);
        k_conv2<<<dim3(T / 256, B), 256, 0, stream>>>(y1, c2w, bn2g, bn2b, bn2m, bn2v, y2t, B, T);
        k_pack_w3<<<dim3(28), 256, 0, stream>>>(c3w, bn3g, bn3v, apk);
        k_conv3m<<<dim3(T / 64, B), 512, 0, stream>>>(y2t, apk, bn3g, bn3b, bn3m, bn3v, feat, B, T);
        k_lstm4<<<dim3(4), 512, 0, stream>>>(feat, w_ih, w_hh, b_ih, b_hh, out, T);
    }
}